// Round 1
// baseline (515.583 us; speedup 1.0000x reference)
//
#include <hip/hip_runtime.h>

typedef unsigned short u16;
typedef unsigned int u32;
typedef short short8 __attribute__((ext_vector_type(8)));
typedef float f32x4 __attribute__((ext_vector_type(4)));

#define LN_EPS 1e-3f
#define PI2 6.28318530717958647692f

__device__ __forceinline__ u16 f2bf(float f) {
  u32 u = __float_as_uint(f);
  u += 0x7fffu + ((u >> 16) & 1u);
  return (u16)(u >> 16);
}
__device__ __forceinline__ float bf2f(u16 h) {
  return __uint_as_float(((u32)h) << 16);
}

// ---------------- weight transpose + bf16 convert: W[R][C] f32 -> Wt[C][R] bf16 ----
__global__ void prep_w(const float* __restrict__ W, u16* __restrict__ Wt, int R, int C) {
  int idx = blockIdx.x * 256 + threadIdx.x;   // grid sized exactly R*C/256
  int n = idx / R;
  int k = idx - n * R;
  Wt[idx] = f2bf(W[(size_t)k * C + n]);
}

// ---------------- x[b][s][d] -> xt[b][d][s] (tiled 32x32) ----------------
__global__ __launch_bounds__(256) void transpose_x(const float* __restrict__ x,
                                                   float* __restrict__ xt) {
  __shared__ float tile[32][33];
  int blk = blockIdx.x;
  int b = blk >> 12;
  int rem = blk & 4095;
  int st = rem >> 4;   // s-tile 0..255
  int dt = rem & 15;   // d-tile 0..15
  int tx = threadIdx.x & 31, ty = threadIdx.x >> 5;
  int s0 = st << 5, d0 = dt << 5;
#pragma unroll
  for (int i = 0; i < 32; i += 8)
    tile[ty + i][tx] = x[(((size_t)(b << 13) + s0 + ty + i) << 9) + d0 + tx];
  __syncthreads();
#pragma unroll
  for (int i = 0; i < 32; i += 8)
    xt[(((size_t)(b << 9) + d0 + ty + i) << 13) + s0 + tx] = tile[tx][ty + i];
}

// ---------------- S-axis FFT (8192-pt DIT), two real columns packed per block ------
// In: X = xt[b][d][s] (real). Out (in-place): X = Re(FFT_S), Xim = Im(FFT_S).
__global__ __launch_bounds__(512) void fft_s(float* __restrict__ X, float* __restrict__ Xim) {
  __shared__ float zr[8192], zi[8192];
  __shared__ float twr[4096], twi[4096];
  const int tid = threadIdx.x;
  const int b = blockIdx.x >> 8;
  const int d0 = (blockIdx.x & 255) << 1;

  for (int k = tid; k < 4096; k += 512) {
    float ang = -PI2 * ((float)k * (1.0f / 8192.0f));
    float s, c;
    sincosf(ang, &s, &c);
    twr[k] = c; twi[k] = s;
  }
  float* r0 = X + (((size_t)(b << 9) + d0) << 13);
  float* r1 = r0 + 8192;
  for (int n = tid; n < 8192; n += 512) {
    int rv = __brev((u32)n) >> 19;          // 13-bit reverse
    zr[rv] = r0[n];                         // col d0 -> real
    zi[rv] = r1[n];                         // col d0+1 -> imag (packed trick)
  }
  __syncthreads();
  for (int st = 1; st <= 13; ++st) {
    const int half = 1 << (st - 1);
#pragma unroll 1
    for (int q = 0; q < 8; ++q) {
      int t = tid + (q << 9);
      int pos = t & (half - 1);
      int i = ((t >> (st - 1)) << st) + pos;
      int j = i + half;
      float wr = twr[pos << (13 - st)], wi = twi[pos << (13 - st)];
      float vr = zr[j], vi = zi[j];
      float tr = vr * wr - vi * wi;
      float ti = vr * wi + vi * wr;
      float ur = zr[i], ui = zi[i];
      zr[i] = ur + tr; zi[i] = ui + ti;
      zr[j] = ur - tr; zi[j] = ui - ti;
    }
    __syncthreads();
  }
  // unpack the two real-input FFTs: A[k]=(Z[k]+conj(Z[N-k]))/2, B[k]=-i(Z[k]-conj(Z[N-k]))/2
  float* i0 = Xim + (((size_t)(b << 9) + d0) << 13);
  float* i1 = i0 + 8192;
  for (int k = tid; k < 8192; k += 512) {
    int nk = (8192 - k) & 8191;
    float zrk = zr[k], zik = zi[k], zrn = zr[nk], zin = zi[nk];
    r0[k] = 0.5f * (zrk + zrn);
    i0[k] = 0.5f * (zik - zin);
    r1[k] = 0.5f * (zik + zin);
    i1[k] = 0.5f * (zrn - zrk);
  }
}

// ---------------- D-axis FFT (512-pt) + residual + LayerNorm1 -> proj bf16 ---------
#define SD 516
__global__ __launch_bounds__(256) void fft_d_ln(
    const float* __restrict__ Xre, const float* __restrict__ Xim,
    const float* __restrict__ x, const float* __restrict__ g1,
    const float* __restrict__ be1, u16* __restrict__ proj) {
  __shared__ float lre[16 * SD];
  __shared__ float lim[16 * SD];
  __shared__ float twr[256], twi[256];
  const int tid = threadIdx.x;
  const int b = blockIdx.x >> 9;
  const int s0 = (blockIdx.x & 511) << 4;

  {
    float ang = -PI2 * ((float)tid * (1.0f / 512.0f));
    float s, c;
    sincosf(ang, &s, &c);
    twr[tid] = c; twi[tid] = s;
  }
  const int so = tid & 15, dd = tid >> 4;
  for (int it = 0; it < 32; ++it) {
    int d = (it << 4) + dd;
    int rd = __brev((u32)d) >> 23;          // 9-bit reverse
    size_t gi = (((size_t)(b << 9) + d) << 13) + s0 + so;
    lre[so * SD + rd] = Xre[gi];
    lim[so * SD + rd] = Xim[gi];
  }
  __syncthreads();
  for (int st = 1; st <= 9; ++st) {
    const int half = 1 << (st - 1);
    int pos = tid & (half - 1);
    int i = ((tid >> (st - 1)) << st) + pos;
    int j = i + half;
    float wr = twr[pos << (9 - st)], wi = twi[pos << (9 - st)];
#pragma unroll 1
    for (int r = 0; r < 16; ++r) {
      float* pr = lre + r * SD;
      float* pi = lim + r * SD;
      float vr = pr[j], vi = pi[j];
      float tr = vr * wr - vi * wi;
      float ti = vr * wi + vi * wr;
      float ur = pr[i], ui = pi[i];
      pr[i] = ur + tr; pi[i] = ui + ti;
      pr[j] = ur - tr; pi[j] = ui - ti;
    }
    __syncthreads();
  }
  // residual add + LN over D=512 (16 threads per row)
  const int row = tid >> 4, c16 = tid & 15;
  const int s = s0 + row;
  const float* xrow = x + (((size_t)(b << 13) + s) << 9);
  float* yrow = lre + row * SD;
  float sum = 0.f, sum2 = 0.f;
#pragma unroll
  for (int m = 0; m < 32; ++m) {
    int d = c16 + (m << 4);
    float v = yrow[d] + xrow[d];
    yrow[d] = v;
    sum += v; sum2 += v * v;
  }
#pragma unroll
  for (int m = 1; m < 16; m <<= 1) {
    sum += __shfl_xor(sum, m, 16);
    sum2 += __shfl_xor(sum2, m, 16);
  }
  float mean = sum * (1.0f / 512.0f);
  float var = sum2 * (1.0f / 512.0f) - mean * mean;
  float scl = 1.0f / sqrtf(var + LN_EPS);
  u16* prow = proj + (((size_t)(b << 13) + s) << 9);
#pragma unroll
  for (int m = 0; m < 32; ++m) {
    int d = c16 + (m << 4);
    float v = (yrow[d] - mean) * scl * g1[d] + be1[d];
    prow[d] = f2bf(v);
  }
}

// ---------------- GEMM: C = act(A[MxK] * Bt[NxK]^T + bias), bf16 MFMA --------------
// m97 structure: 128x128 tile, 4 waves, BK=64, global_load_lds w16, XOR-swizzled LDS.
template <bool RELU, bool OUT_BF16>
__global__ __launch_bounds__(256, 2) void gemm_bt(
    const u16* __restrict__ A, const u16* __restrict__ Bt,
    const float* __restrict__ bias, void* __restrict__ Cout,
    int M, int N, int K) {
  const int tid = threadIdx.x;
  const int lane = tid & 63;
  const int wave = tid >> 6;
  const int wm = wave >> 1, wn = wave & 1;
  const int llo = lane & 15, lhi = lane >> 4;

  const int nwg = gridDim.x;                 // divisible by 8 for both launches
  const int q = nwg >> 3;
  const int b2 = ((int)blockIdx.x & 7) * q + ((int)blockIdx.x >> 3);  // XCD swizzle
  const int MT = M >> 7;
  const int tm = b2 % MT;
  const int tn = b2 / MT;
  const int m0 = tm << 7, n0 = tn << 7;

  __shared__ short8 smem[2048];              // 32 KB: A tile 16K + B tile 16K
  char* ldsA = (char*)&smem[0];
  char* ldsB = ldsA + 16384;

  f32x4 acc[4][4] = {};

  const int trow = tid >> 3;                                  // staging row 0..31
  const int ksw = (((tid & 7) ^ (trow & 7)) << 3);            // inverse-swizzled source k
  const int wbase = wave << 10;                               // wave-uniform LDS base
  const int swz = (llo & 7) << 4;                             // read-side XOR

  const int KT = K >> 6;
  for (int kt = 0; kt < KT; ++kt) {
    const int k0 = (kt << 6) + ksw;
    __syncthreads();                          // all waves done reading previous tile
#pragma unroll
    for (int r = 0; r < 4; ++r) {
      const int grow = (r << 5) + trow;
      const u16* ga = A + (size_t)(m0 + grow) * K + k0;
      const u16* gb = Bt + (size_t)(n0 + grow) * K + k0;
      __builtin_amdgcn_global_load_lds(
          (const __attribute__((address_space(1))) void*)ga,
          (__attribute__((address_space(3))) void*)(ldsA + (r << 12) + wbase), 16, 0, 0);
      __builtin_amdgcn_global_load_lds(
          (const __attribute__((address_space(1))) void*)gb,
          (__attribute__((address_space(3))) void*)(ldsB + (r << 12) + wbase), 16, 0, 0);
    }
    __syncthreads();                          // compiler drains vmcnt(0) here
#pragma unroll
    for (int kk = 0; kk < 2; ++kk) {
      const int cbx = ((kk << 6) | (lhi << 4)) ^ swz;
      short8 af[4], bfr[4];
#pragma unroll
      for (int mt = 0; mt < 4; ++mt)
        af[mt] = *(const short8*)(ldsA + (((wm << 6) + (mt << 4) + llo) << 7) + cbx);
#pragma unroll
      for (int nt = 0; nt < 4; ++nt)
        bfr[nt] = *(const short8*)(ldsB + (((wn << 6) + (nt << 4) + llo) << 7) + cbx);
#pragma unroll
      for (int mt = 0; mt < 4; ++mt)
#pragma unroll
        for (int nt = 0; nt < 4; ++nt)
          acc[mt][nt] =
              __builtin_amdgcn_mfma_f32_16x16x32_bf16(af[mt], bfr[nt], acc[mt][nt], 0, 0, 0);
    }
  }
  // epilogue: C/D map col=lane&15, row=(lane>>4)*4+j (guide-verified)
#pragma unroll
  for (int nt = 0; nt < 4; ++nt) {
    const int col = n0 + (wn << 6) + (nt << 4) + llo;
    const float bv = bias[col];
#pragma unroll
    for (int mt = 0; mt < 4; ++mt) {
      const int rbase = m0 + (wm << 6) + (mt << 4) + (lhi << 2);
#pragma unroll
      for (int j = 0; j < 4; ++j) {
        float v = acc[mt][nt][j] + bv;
        if (RELU) v = fmaxf(v, 0.0f);
        if (OUT_BF16) ((u16*)Cout)[(size_t)(rbase + j) * N + col] = f2bf(v);
        else          ((float*)Cout)[(size_t)(rbase + j) * N + col] = v;
      }
    }
  }
}

// ---------------- final residual + LayerNorm2 (wave per row, in-place on d_out) ----
__global__ __launch_bounds__(256) void ln2_kernel(
    float* __restrict__ out, const u16* __restrict__ proj,
    const float* __restrict__ g2, const float* __restrict__ be2) {
  const int lane = threadIdx.x & 63;
  const int row = blockIdx.x * 4 + (threadIdx.x >> 6);
  float* orow = out + ((size_t)row << 9);
  const u16* prow = proj + ((size_t)row << 9);
  float y[8];
  float sum = 0.f, sum2 = 0.f;
#pragma unroll
  for (int m = 0; m < 8; ++m) {
    int d = lane + (m << 6);
    float v = orow[d] + bf2f(prow[d]);
    y[m] = v; sum += v; sum2 += v * v;
  }
#pragma unroll
  for (int m = 1; m < 64; m <<= 1) {
    sum += __shfl_xor(sum, m, 64);
    sum2 += __shfl_xor(sum2, m, 64);
  }
  float mean = sum * (1.0f / 512.0f);
  float var = sum2 * (1.0f / 512.0f) - mean * mean;
  float scl = 1.0f / sqrtf(var + LN_EPS);
#pragma unroll
  for (int m = 0; m < 8; ++m) {
    int d = lane + (m << 6);
    orow[d] = (y[m] - mean) * scl * g2[d] + be2[d];
  }
}

// ---------------- launch ----------------
extern "C" void kernel_launch(void* const* d_in, const int* in_sizes, int n_in,
                              void* d_out, int out_size, void* d_ws, size_t ws_size,
                              hipStream_t stream) {
  const float* x   = (const float*)d_in[0];
  const float* W1  = (const float*)d_in[1];
  const float* b1  = (const float*)d_in[2];
  const float* W2  = (const float*)d_in[3];
  const float* b2  = (const float*)d_in[4];
  const float* g1  = (const float*)d_in[5];
  const float* be1 = (const float*)d_in[6];
  const float* g2  = (const float*)d_in[7];
  const float* be2 = (const float*)d_in[8];

  char* ws = (char*)d_ws;
  // layout (164 MB total):
  //   [0,64M)    xt -> Xre (in-place) -> first half of h
  //   [64M,128M) Xim -> second half of h
  //   [128M,160M) proj bf16
  //   [160M,162M) W1T bf16   [162M,164M) W2T bf16
  float* xre  = (float*)(ws);
  float* xim  = (float*)(ws + (64u << 20));
  u16*   proj = (u16*)(ws + (128u << 20));
  u16*   w1t  = (u16*)(ws + (160u << 20));
  u16*   w2t  = (u16*)(ws + (162u << 20));
  u16*   h    = (u16*)(ws);                  // 128 MB, aliases xre+xim (dead by then)

  prep_w<<<4096, 256, 0, stream>>>(W1, w1t, 512, 2048);
  prep_w<<<4096, 256, 0, stream>>>(W2, w2t, 2048, 512);
  transpose_x<<<16384, 256, 0, stream>>>(x, xre);
  fft_s<<<1024, 512, 0, stream>>>(xre, xim);
  fft_d_ln<<<2048, 256, 0, stream>>>(xre, xim, x, g1, be1, proj);
  gemm_bt<true, true><<<4096, 256, 0, stream>>>(proj, w1t, b1, (void*)h, 32768, 2048, 512);
  gemm_bt<false, false><<<1024, 256, 0, stream>>>(h, w2t, b2, d_out, 32768, 512, 2048);
  ln2_kernel<<<8192, 256, 0, stream>>>((float*)d_out, proj, g2, be2);
  (void)in_sizes; (void)n_in; (void)out_size; (void)ws_size;
}

// Round 2
// 401.492 us; speedup vs baseline: 1.2842x; 1.2842x over previous
//
#include <hip/hip_runtime.h>

typedef unsigned short u16;
typedef unsigned int u32;
typedef short short8 __attribute__((ext_vector_type(8)));
typedef float f32x4 __attribute__((ext_vector_type(4)));

#define LN_EPS 1e-3f
#define PI2 6.28318530717958647692f

__device__ __forceinline__ u16 f2bf(float f) {
  u32 u = __float_as_uint(f);
  u += 0x7fffu + ((u >> 16) & 1u);
  return (u16)(u >> 16);
}
__device__ __forceinline__ float bf2f(u16 h) {
  return __uint_as_float(((u32)h) << 16);
}

// ---------------- weight transpose + bf16 convert: W[R][C] f32 -> Wt[C][R] bf16 ----
__global__ void prep_w(const float* __restrict__ W, u16* __restrict__ Wt, int R, int C) {
  int idx = blockIdx.x * 256 + threadIdx.x;   // grid sized exactly R*C/256
  int n = idx / R;
  int k = idx - n * R;
  Wt[idx] = f2bf(W[(size_t)k * C + n]);
}

// ---------------- x[b][s][d] -> xt[b][d][s] (tiled 32x32) ----------------
__global__ __launch_bounds__(256) void transpose_x(const float* __restrict__ x,
                                                   float* __restrict__ xt) {
  __shared__ float tile[32][33];
  int blk = blockIdx.x;
  int b = blk >> 12;
  int rem = blk & 4095;
  int st = rem >> 4;   // s-tile 0..255
  int dt = rem & 15;   // d-tile 0..15
  int tx = threadIdx.x & 31, ty = threadIdx.x >> 5;
  int s0 = st << 5, d0 = dt << 5;
#pragma unroll
  for (int i = 0; i < 32; i += 8)
    tile[ty + i][tx] = x[(((size_t)(b << 13) + s0 + ty + i) << 9) + d0 + tx];
  __syncthreads();
#pragma unroll
  for (int i = 0; i < 32; i += 8)
    xt[(((size_t)(b << 9) + d0 + ty + i) << 13) + s0 + tx] = tile[tx][ty + i];
}

// ---------------- S-axis FFT (8192-pt DIF, register-blocked radix-16) --------------
// Two real columns packed per complex FFT. In: X=xt[b][d][s]. Out in-place:
// X = Re(FFT_S), Xim = Im(FFT_S).
// Twiddle constant tables W_n^k = exp(-2*pi*i*k/n): (cos, -sin)
__device__ __constant__ float C16r[8] = {1.f, 0.92387953f, 0.70710678f, 0.38268343f,
                                         0.f, -0.38268343f, -0.70710678f, -0.92387953f};
__device__ __constant__ float C16i[8] = {0.f, -0.38268343f, -0.70710678f, -0.92387953f,
                                         -1.f, -0.92387953f, -0.70710678f, -0.38268343f};
__device__ __constant__ float C8r[4] = {1.f, 0.70710678f, 0.f, -0.70710678f};
__device__ __constant__ float C8i[4] = {0.f, -0.70710678f, -1.f, -0.70710678f};
__device__ __constant__ float C4r[2] = {1.f, 0.f};
__device__ __constant__ float C4i[2] = {0.f, -1.f};
__device__ __constant__ float C32r[16] = {
    1.f, 0.98078528f, 0.92387953f, 0.83146961f, 0.70710678f, 0.55557023f,
    0.38268343f, 0.19509032f, 0.f, -0.19509032f, -0.38268343f, -0.55557023f,
    -0.70710678f, -0.83146961f, -0.92387953f, -0.98078528f};
__device__ __constant__ float C32i[16] = {
    0.f, -0.19509032f, -0.38268343f, -0.55557023f, -0.70710678f, -0.83146961f,
    -0.92387953f, -0.98078528f, -1.f, -0.98078528f, -0.92387953f, -0.83146961f,
    -0.70710678f, -0.55557023f, -0.38268343f, -0.19509032f};
__device__ __constant__ int REV4[16] = {0, 8, 4, 12, 2, 10, 6, 14,
                                        1, 9, 5, 13, 3, 11, 7, 15};

#define BFLY(ar, ai, br, bi, wr, wi)                 \
  {                                                  \
    float dr_ = (ar) - (br), di_ = (ai) - (bi);      \
    (ar) += (br);                                    \
    (ai) += (bi);                                    \
    (br) = dr_ * (wr)-di_ * (wi);                    \
    (bi) = dr_ * (wi) + di_ * (wr);                  \
  }

__global__ __launch_bounds__(512) void fft_s(float* __restrict__ X, float* __restrict__ Xim) {
  __shared__ float zr[8448], zi[8448];      // padded: addr(i) = i + (i>>5)
  const int t = threadIdx.x;
  const int b = blockIdx.x >> 8;
  const int d0 = (blockIdx.x & 255) << 1;
  float* r0 = X + (((size_t)(b << 9) + d0) << 13);
  float* r1 = r0 + 8192;

  float xr[16], xi[16];
#pragma unroll
  for (int e = 0; e < 16; ++e) {            // coalesced loads, idx = t + 512e
    xr[e] = r0[t + (e << 9)];
    xi[e] = r1[t + (e << 9)];
  }

  // ---- pass A: strides 4096,2048,1024,512 in-register ----
  float c1, s1;
  sincosf(-PI2 * (float)t * (1.0f / 8192.0f), &s1, &c1);
  float c2 = c1 * c1 - s1 * s1, s2 = 2.f * c1 * s1;
  float c4 = c2 * c2 - s2 * s2, s4 = 2.f * c2 * s2;
  float c8 = c4 * c4 - s4 * s4, s8 = 2.f * c4 * s4;
#pragma unroll
  for (int e = 0; e < 8; ++e) {             // m=8192
    float wr = c1 * C16r[e] - s1 * C16i[e];
    float wi = c1 * C16i[e] + s1 * C16r[e];
    BFLY(xr[e], xi[e], xr[e + 8], xi[e + 8], wr, wi);
  }
#pragma unroll
  for (int e = 0; e < 16; ++e) {            // m=4096: pairs (e,e+4), bit2==0
    if ((e & 4) == 0 && ((e >> 3) == (e >> 3))) {
      if ((e & 4) == 0) {
        int eb = e & 3;
        float wr = c2 * C8r[eb] - s2 * C8i[eb];
        float wi = c2 * C8i[eb] + s2 * C8r[eb];
        if (((e >> 2) & 1) == 0) BFLY(xr[e], xi[e], xr[e + 4], xi[e + 4], wr, wi);
      }
    }
  }
#pragma unroll
  for (int e = 0; e < 16; ++e) {            // m=2048: pairs (e,e+2), bit1==0
    if (((e >> 1) & 1) == 0) {
      int eb = e & 1;
      float wr = c4 * C4r[eb] - s4 * C4i[eb];
      float wi = c4 * C4i[eb] + s4 * C4r[eb];
      BFLY(xr[e], xi[e], xr[e + 2], xi[e + 2], wr, wi);
    }
  }
#pragma unroll
  for (int e = 0; e < 16; e += 2) {         // m=1024: pairs (e,e+1)
    BFLY(xr[e], xi[e], xr[e + 1], xi[e + 1], c8, s8);
  }

  // ---- exchange A->B ----
#pragma unroll
  for (int e = 0; e < 16; ++e) {
    int idx = t + (e << 9);
    int a = idx + (idx >> 5);
    zr[a] = xr[e];
    zi[a] = xi[e];
  }
  __syncthreads();
  {
    const int f = t >> 5, l = t & 31;
#pragma unroll
    for (int e = 0; e < 16; ++e) {
      int idx = (f << 9) + (e << 5) + l;
      int a = idx + (idx >> 5);
      xr[e] = zr[a];
      xi[e] = zi[a];
    }
    // ---- pass B: strides 256,128,64,32 in-register (within 512-block f) ----
    float bc1, bs1;
    sincosf(-PI2 * (float)l * (1.0f / 512.0f), &bs1, &bc1);
    float bc2 = bc1 * bc1 - bs1 * bs1, bs2 = 2.f * bc1 * bs1;
    float bc4 = bc2 * bc2 - bs2 * bs2, bs4 = 2.f * bc2 * bs2;
    float bc8 = bc4 * bc4 - bs4 * bs4, bs8 = 2.f * bc4 * bs4;
#pragma unroll
    for (int e = 0; e < 8; ++e) {           // m=512
      float wr = bc1 * C16r[e] - bs1 * C16i[e];
      float wi = bc1 * C16i[e] + bs1 * C16r[e];
      BFLY(xr[e], xi[e], xr[e + 8], xi[e + 8], wr, wi);
    }
#pragma unroll
    for (int e = 0; e < 16; ++e) {          // m=256
      if (((e >> 2) & 1) == 0) {
        int eb = e & 3;
        float wr = bc2 * C8r[eb] - bs2 * C8i[eb];
        float wi = bc2 * C8i[eb] + bs2 * C8r[eb];
        BFLY(xr[e], xi[e], xr[e + 4], xi[e + 4], wr, wi);
      }
    }
#pragma unroll
    for (int e = 0; e < 16; ++e) {          // m=128
      if (((e >> 1) & 1) == 0) {
        int eb = e & 1;
        float wr = bc4 * C4r[eb] - bs4 * C4i[eb];
        float wi = bc4 * C4i[eb] + bs4 * C4r[eb];
        BFLY(xr[e], xi[e], xr[e + 2], xi[e + 2], wr, wi);
      }
    }
#pragma unroll
    for (int e = 0; e < 16; e += 2) {       // m=64
      BFLY(xr[e], xi[e], xr[e + 1], xi[e + 1], bc8, bs8);
    }
    // ---- exchange B->C ----
    __syncthreads();
#pragma unroll
    for (int e = 0; e < 16; ++e) {
      int idx = (f << 9) + (e << 5) + l;
      int a = idx + (idx >> 5);
      zr[a] = xr[e];
      zi[a] = xi[e];
    }
  }
  __syncthreads();
#pragma unroll
  for (int j = 0; j < 16; ++j) {
    int idx = (t << 4) + j;
    int a = idx + (idx >> 5);
    xr[j] = zr[a];
    xi[j] = zi[a];
  }

  // ---- pass C: stride 16 via shfl, then 8,4,2,1 in-register ----
  {
    const int odd = t & 1;
#pragma unroll
    for (int j = 0; j < 16; ++j) {          // m=32 across thread pair
      float pr = __shfl_xor(xr[j], 1);
      float pi = __shfl_xor(xi[j], 1);
      if (!odd) {
        xr[j] += pr;
        xi[j] += pi;
      } else {
        float dr = pr - xr[j], di = pi - xi[j];   // a - b (a = partner)
        xr[j] = dr * C32r[j] - di * C32i[j];
        xi[j] = dr * C32i[j] + di * C32r[j];
      }
    }
#pragma unroll
    for (int j = 0; j < 8; ++j) {           // m=16
      BFLY(xr[j], xi[j], xr[j + 8], xi[j + 8], C16r[j], C16i[j]);
    }
#pragma unroll
    for (int j = 0; j < 16; ++j) {          // m=8
      if (((j >> 2) & 1) == 0) {
        BFLY(xr[j], xi[j], xr[j + 4], xi[j + 4], C8r[j & 3], C8i[j & 3]);
      }
    }
#pragma unroll
    for (int j = 0; j < 16; ++j) {          // m=4
      if (((j >> 1) & 1) == 0) {
        BFLY(xr[j], xi[j], xr[j + 2], xi[j + 2], C4r[j & 1], C4i[j & 1]);
      }
    }
#pragma unroll
    for (int j = 0; j < 16; j += 2) {       // m=2, tw = 1
      BFLY(xr[j], xi[j], xr[j + 1], xi[j + 1], 1.0f, 0.0f);
    }
  }

  // ---- bit-reversal scatter: z[16t+j] = X[rev13(16t+j)] ----
  __syncthreads();
  {
    const int rt = __brev((u32)t) >> 23;    // 9-bit reverse
#pragma unroll
    for (int j = 0; j < 16; ++j) {
      int k = (REV4[j] << 9) | rt;
      int a = k + (k >> 5);
      zr[a] = xr[j];
      zi[a] = xi[j];
    }
  }
  __syncthreads();

  // ---- unpack two real FFTs + coalesced store ----
  float* i0 = Xim + (((size_t)(b << 9) + d0) << 13);
  float* i1 = i0 + 8192;
#pragma unroll
  for (int e = 0; e < 16; ++e) {
    int k = t + (e << 9);
    int nk = (8192 - k) & 8191;
    int ka = k + (k >> 5), na = nk + (nk >> 5);
    float zrk = zr[ka], zik = zi[ka], zrn = zr[na], zin = zi[na];
    r0[k] = 0.5f * (zrk + zrn);
    i0[k] = 0.5f * (zik - zin);
    r1[k] = 0.5f * (zik + zin);
    i1[k] = 0.5f * (zrn - zrk);
  }
}

// ---------------- D-axis FFT (512-pt) + residual + LayerNorm1 -> proj bf16 ---------
#define SD 516
__global__ __launch_bounds__(256) void fft_d_ln(
    const float* __restrict__ Xre, const float* __restrict__ Xim,
    const float* __restrict__ x, const float* __restrict__ g1,
    const float* __restrict__ be1, u16* __restrict__ proj) {
  __shared__ float lre[16 * SD];
  __shared__ float lim[16 * SD];
  __shared__ float twr[256], twi[256];
  const int tid = threadIdx.x;
  const int b = blockIdx.x >> 9;
  const int s0 = (blockIdx.x & 511) << 4;

  {
    float ang = -PI2 * ((float)tid * (1.0f / 512.0f));
    float s, c;
    sincosf(ang, &s, &c);
    twr[tid] = c; twi[tid] = s;
  }
  const int so = tid & 15, dd = tid >> 4;
  for (int it = 0; it < 32; ++it) {
    int d = (it << 4) + dd;
    int rd = __brev((u32)d) >> 23;          // 9-bit reverse
    size_t gi = (((size_t)(b << 9) + d) << 13) + s0 + so;
    lre[so * SD + rd] = Xre[gi];
    lim[so * SD + rd] = Xim[gi];
  }
  __syncthreads();
  for (int st = 1; st <= 9; ++st) {
    const int half = 1 << (st - 1);
    int pos = tid & (half - 1);
    int i = ((tid >> (st - 1)) << st) + pos;
    int j = i + half;
    float wr = twr[pos << (9 - st)], wi = twi[pos << (9 - st)];
#pragma unroll 1
    for (int r = 0; r < 16; ++r) {
      float* pr = lre + r * SD;
      float* pi = lim + r * SD;
      float vr = pr[j], vi = pi[j];
      float tr = vr * wr - vi * wi;
      float ti = vr * wi + vi * wr;
      float ur = pr[i], ui = pi[i];
      pr[i] = ur + tr; pi[i] = ui + ti;
      pr[j] = ur - tr; pi[j] = ui - ti;
    }
    __syncthreads();
  }
  // residual add + LN over D=512 (16 threads per row)
  const int row = tid >> 4, c16 = tid & 15;
  const int s = s0 + row;
  const float* xrow = x + (((size_t)(b << 13) + s) << 9);
  float* yrow = lre + row * SD;
  float sum = 0.f, sum2 = 0.f;
#pragma unroll
  for (int m = 0; m < 32; ++m) {
    int d = c16 + (m << 4);
    float v = yrow[d] + xrow[d];
    yrow[d] = v;
    sum += v; sum2 += v * v;
  }
#pragma unroll
  for (int m = 1; m < 16; m <<= 1) {
    sum += __shfl_xor(sum, m, 16);
    sum2 += __shfl_xor(sum2, m, 16);
  }
  float mean = sum * (1.0f / 512.0f);
  float var = sum2 * (1.0f / 512.0f) - mean * mean;
  float scl = 1.0f / sqrtf(var + LN_EPS);
  u16* prow = proj + (((size_t)(b << 13) + s) << 9);
#pragma unroll
  for (int m = 0; m < 32; ++m) {
    int d = c16 + (m << 4);
    float v = (yrow[d] - mean) * scl * g1[d] + be1[d];
    prow[d] = f2bf(v);
  }
}

// ---------------- GEMM: C = act(A[MxK] * Bt[NxK]^T + bias), bf16 MFMA --------------
// m97 structure: 128x128 tile, 4 waves, BK=64, global_load_lds w16, XOR-swizzled LDS.
template <bool RELU, bool OUT_BF16>
__global__ __launch_bounds__(256, 2) void gemm_bt(
    const u16* __restrict__ A, const u16* __restrict__ Bt,
    const float* __restrict__ bias, void* __restrict__ Cout,
    int M, int N, int K) {
  const int tid = threadIdx.x;
  const int lane = tid & 63;
  const int wave = tid >> 6;
  const int wm = wave >> 1, wn = wave & 1;
  const int llo = lane & 15, lhi = lane >> 4;

  const int nwg = gridDim.x;                 // divisible by 8 for both launches
  const int q = nwg >> 3;
  const int b2 = ((int)blockIdx.x & 7) * q + ((int)blockIdx.x >> 3);  // XCD swizzle
  const int MT = M >> 7;
  const int tm = b2 % MT;
  const int tn = b2 / MT;
  const int m0 = tm << 7, n0 = tn << 7;

  __shared__ short8 smem[2048];              // 32 KB: A tile 16K + B tile 16K
  char* ldsA = (char*)&smem[0];
  char* ldsB = ldsA + 16384;

  f32x4 acc[4][4] = {};

  const int trow = tid >> 3;                                  // staging row 0..31
  const int ksw = (((tid & 7) ^ (trow & 7)) << 3);            // inverse-swizzled source k
  const int wbase = wave << 10;                               // wave-uniform LDS base
  const int swz = (llo & 7) << 4;                             // read-side XOR

  const int KT = K >> 6;
  for (int kt = 0; kt < KT; ++kt) {
    const int k0 = (kt << 6) + ksw;
    __syncthreads();                          // all waves done reading previous tile
#pragma unroll
    for (int r = 0; r < 4; ++r) {
      const int grow = (r << 5) + trow;
      const u16* ga = A + (size_t)(m0 + grow) * K + k0;
      const u16* gb = Bt + (size_t)(n0 + grow) * K + k0;
      __builtin_amdgcn_global_load_lds(
          (const __attribute__((address_space(1))) void*)ga,
          (__attribute__((address_space(3))) void*)(ldsA + (r << 12) + wbase), 16, 0, 0);
      __builtin_amdgcn_global_load_lds(
          (const __attribute__((address_space(1))) void*)gb,
          (__attribute__((address_space(3))) void*)(ldsB + (r << 12) + wbase), 16, 0, 0);
    }
    __syncthreads();                          // compiler drains vmcnt(0) here
#pragma unroll
    for (int kk = 0; kk < 2; ++kk) {
      const int cbx = ((kk << 6) | (lhi << 4)) ^ swz;
      short8 af[4], bfr[4];
#pragma unroll
      for (int mt = 0; mt < 4; ++mt)
        af[mt] = *(const short8*)(ldsA + (((wm << 6) + (mt << 4) + llo) << 7) + cbx);
#pragma unroll
      for (int nt = 0; nt < 4; ++nt)
        bfr[nt] = *(const short8*)(ldsB + (((wn << 6) + (nt << 4) + llo) << 7) + cbx);
#pragma unroll
      for (int mt = 0; mt < 4; ++mt)
#pragma unroll
        for (int nt = 0; nt < 4; ++nt)
          acc[mt][nt] =
              __builtin_amdgcn_mfma_f32_16x16x32_bf16(af[mt], bfr[nt], acc[mt][nt], 0, 0, 0);
    }
  }
  // epilogue: C/D map col=lane&15, row=(lane>>4)*4+j (guide-verified)
#pragma unroll
  for (int nt = 0; nt < 4; ++nt) {
    const int col = n0 + (wn << 6) + (nt << 4) + llo;
    const float bv = bias[col];
#pragma unroll
    for (int mt = 0; mt < 4; ++mt) {
      const int rbase = m0 + (wm << 6) + (mt << 4) + (lhi << 2);
#pragma unroll
      for (int j = 0; j < 4; ++j) {
        float v = acc[mt][nt][j] + bv;
        if (RELU) v = fmaxf(v, 0.0f);
        if (OUT_BF16) ((u16*)Cout)[(size_t)(rbase + j) * N + col] = f2bf(v);
        else          ((float*)Cout)[(size_t)(rbase + j) * N + col] = v;
      }
    }
  }
}

// ---------------- final residual + LayerNorm2 (wave per row, in-place on d_out) ----
__global__ __launch_bounds__(256) void ln2_kernel(
    float* __restrict__ out, const u16* __restrict__ proj,
    const float* __restrict__ g2, const float* __restrict__ be2) {
  const int lane = threadIdx.x & 63;
  const int row = blockIdx.x * 4 + (threadIdx.x >> 6);
  float* orow = out + ((size_t)row << 9);
  const u16* prow = proj + ((size_t)row << 9);
  float y[8];
  float sum = 0.f, sum2 = 0.f;
#pragma unroll
  for (int m = 0; m < 8; ++m) {
    int d = lane + (m << 6);
    float v = orow[d] + bf2f(prow[d]);
    y[m] = v; sum += v; sum2 += v * v;
  }
#pragma unroll
  for (int m = 1; m < 64; m <<= 1) {
    sum += __shfl_xor(sum, m, 64);
    sum2 += __shfl_xor(sum2, m, 64);
  }
  float mean = sum * (1.0f / 512.0f);
  float var = sum2 * (1.0f / 512.0f) - mean * mean;
  float scl = 1.0f / sqrtf(var + LN_EPS);
#pragma unroll
  for (int m = 0; m < 8; ++m) {
    int d = lane + (m << 6);
    orow[d] = (y[m] - mean) * scl * g2[d] + be2[d];
  }
}

// ---------------- launch ----------------
extern "C" void kernel_launch(void* const* d_in, const int* in_sizes, int n_in,
                              void* d_out, int out_size, void* d_ws, size_t ws_size,
                              hipStream_t stream) {
  const float* x   = (const float*)d_in[0];
  const float* W1  = (const float*)d_in[1];
  const float* b1  = (const float*)d_in[2];
  const float* W2  = (const float*)d_in[3];
  const float* b2  = (const float*)d_in[4];
  const float* g1  = (const float*)d_in[5];
  const float* be1 = (const float*)d_in[6];
  const float* g2  = (const float*)d_in[7];
  const float* be2 = (const float*)d_in[8];

  char* ws = (char*)d_ws;
  // layout (164 MB total):
  //   [0,64M)    xt -> Xre (in-place) -> first half of h
  //   [64M,128M) Xim -> second half of h
  //   [128M,160M) proj bf16
  //   [160M,162M) W1T bf16   [162M,164M) W2T bf16
  float* xre  = (float*)(ws);
  float* xim  = (float*)(ws + (64u << 20));
  u16*   proj = (u16*)(ws + (128u << 20));
  u16*   w1t  = (u16*)(ws + (160u << 20));
  u16*   w2t  = (u16*)(ws + (162u << 20));
  u16*   h    = (u16*)(ws);                  // 128 MB, aliases xre+xim (dead by then)

  prep_w<<<4096, 256, 0, stream>>>(W1, w1t, 512, 2048);
  prep_w<<<4096, 256, 0, stream>>>(W2, w2t, 2048, 512);
  transpose_x<<<16384, 256, 0, stream>>>(x, xre);
  fft_s<<<1024, 512, 0, stream>>>(xre, xim);
  fft_d_ln<<<2048, 256, 0, stream>>>(xre, xim, x, g1, be1, proj);
  gemm_bt<true, true><<<4096, 256, 0, stream>>>(proj, w1t, b1, (void*)h, 32768, 2048, 512);
  gemm_bt<false, false><<<1024, 256, 0, stream>>>(h, w2t, b2, d_out, 32768, 512, 2048);
  ln2_kernel<<<8192, 256, 0, stream>>>((float*)d_out, proj, g2, be2);
  (void)in_sizes; (void)n_in; (void)out_size; (void)ws_size;
}

// Round 3
// 362.708 us; speedup vs baseline: 1.4215x; 1.1069x over previous
//
#include <hip/hip_runtime.h>

typedef unsigned short u16;
typedef unsigned int u32;
typedef short short8 __attribute__((ext_vector_type(8)));
typedef float f32x4 __attribute__((ext_vector_type(4)));

#define LN_EPS 1e-3f
#define PI2 6.28318530717958647692f

__device__ __forceinline__ u16 f2bf(float f) {
  u32 u = __float_as_uint(f);
  u += 0x7fffu + ((u >> 16) & 1u);
  return (u16)(u >> 16);
}
__device__ __forceinline__ float bf2f(u16 h) {
  return __uint_as_float(((u32)h) << 16);
}

// ---------------- weight transpose + bf16 convert: W[R][C] f32 -> Wt[C][R] bf16 ----
__global__ void prep_w(const float* __restrict__ W, u16* __restrict__ Wt, int R, int C) {
  int idx = blockIdx.x * 256 + threadIdx.x;   // grid sized exactly R*C/256
  int n = idx / R;
  int k = idx - n * R;
  Wt[idx] = f2bf(W[(size_t)k * C + n]);
}

// ---------------- x[b][s][d] -> xt[b][d][s] (tiled 32x32) ----------------
__global__ __launch_bounds__(256) void transpose_x(const float* __restrict__ x,
                                                   float* __restrict__ xt) {
  __shared__ float tile[32][33];
  int blk = blockIdx.x;
  int b = blk >> 12;
  int rem = blk & 4095;
  int st = rem >> 4;   // s-tile 0..255
  int dt = rem & 15;   // d-tile 0..15
  int tx = threadIdx.x & 31, ty = threadIdx.x >> 5;
  int s0 = st << 5, d0 = dt << 5;
#pragma unroll
  for (int i = 0; i < 32; i += 8)
    tile[ty + i][tx] = x[(((size_t)(b << 13) + s0 + ty + i) << 9) + d0 + tx];
  __syncthreads();
#pragma unroll
  for (int i = 0; i < 32; i += 8)
    xt[(((size_t)(b << 9) + d0 + ty + i) << 13) + s0 + tx] = tile[tx][ty + i];
}

// ---------------- S-axis FFT (8192-pt DIF, register-blocked radix-16) --------------
// Two real columns packed per complex FFT. In: X=xt[b][d][s]. Out in-place:
// X = Re(FFT_S), Xim = Im(FFT_S).
// Twiddle constant tables W_n^k = exp(-2*pi*i*k/n): (cos, -sin)
__device__ __constant__ float C16r[8] = {1.f, 0.92387953f, 0.70710678f, 0.38268343f,
                                         0.f, -0.38268343f, -0.70710678f, -0.92387953f};
__device__ __constant__ float C16i[8] = {0.f, -0.38268343f, -0.70710678f, -0.92387953f,
                                         -1.f, -0.92387953f, -0.70710678f, -0.38268343f};
__device__ __constant__ float C8r[4] = {1.f, 0.70710678f, 0.f, -0.70710678f};
__device__ __constant__ float C8i[4] = {0.f, -0.70710678f, -1.f, -0.70710678f};
__device__ __constant__ float C4r[2] = {1.f, 0.f};
__device__ __constant__ float C4i[2] = {0.f, -1.f};
__device__ __constant__ float C32r[16] = {
    1.f, 0.98078528f, 0.92387953f, 0.83146961f, 0.70710678f, 0.55557023f,
    0.38268343f, 0.19509032f, 0.f, -0.19509032f, -0.38268343f, -0.55557023f,
    -0.70710678f, -0.83146961f, -0.92387953f, -0.98078528f};
__device__ __constant__ float C32i[16] = {
    0.f, -0.19509032f, -0.38268343f, -0.55557023f, -0.70710678f, -0.83146961f,
    -0.92387953f, -0.98078528f, -1.f, -0.98078528f, -0.92387953f, -0.83146961f,
    -0.70710678f, -0.55557023f, -0.38268343f, -0.19509032f};
__device__ __constant__ int REV4[16] = {0, 8, 4, 12, 2, 10, 6, 14,
                                        1, 9, 5, 13, 3, 11, 7, 15};

__device__ __forceinline__ constexpr int rev4c(int v) {
  return ((v & 1) << 3) | ((v & 2) << 1) | ((v & 4) >> 1) | ((v & 8) >> 3);
}

#define BFLY(ar, ai, br, bi, wr, wi)                 \
  {                                                  \
    float dr_ = (ar) - (br), di_ = (ai) - (bi);      \
    (ar) += (br);                                    \
    (ai) += (bi);                                    \
    (br) = dr_ * (wr)-di_ * (wi);                    \
    (bi) = dr_ * (wi) + di_ * (wr);                  \
  }

__global__ __launch_bounds__(512) void fft_s(float* __restrict__ X, float* __restrict__ Xim) {
  __shared__ float zr[8448], zi[8448];      // padded: addr(i) = i + (i>>5)
  const int t = threadIdx.x;
  const int b = blockIdx.x >> 8;
  const int d0 = (blockIdx.x & 255) << 1;
  float* r0 = X + (((size_t)(b << 9) + d0) << 13);
  float* r1 = r0 + 8192;

  float xr[16], xi[16];
#pragma unroll
  for (int e = 0; e < 16; ++e) {            // coalesced loads, idx = t + 512e
    xr[e] = r0[t + (e << 9)];
    xi[e] = r1[t + (e << 9)];
  }

  // ---- pass A: strides 4096,2048,1024,512 in-register ----
  float c1, s1;
  sincosf(-PI2 * (float)t * (1.0f / 8192.0f), &s1, &c1);
  float c2 = c1 * c1 - s1 * s1, s2 = 2.f * c1 * s1;
  float c4 = c2 * c2 - s2 * s2, s4 = 2.f * c2 * s2;
  float c8 = c4 * c4 - s4 * s4, s8 = 2.f * c4 * s4;
#pragma unroll
  for (int e = 0; e < 8; ++e) {             // m=8192
    float wr = c1 * C16r[e] - s1 * C16i[e];
    float wi = c1 * C16i[e] + s1 * C16r[e];
    BFLY(xr[e], xi[e], xr[e + 8], xi[e + 8], wr, wi);
  }
#pragma unroll
  for (int e = 0; e < 16; ++e) {            // m=4096: pairs (e,e+4), bit2==0
    if ((e & 4) == 0) {
      int eb = e & 3;
      float wr = c2 * C8r[eb] - s2 * C8i[eb];
      float wi = c2 * C8i[eb] + s2 * C8r[eb];
      BFLY(xr[e], xi[e], xr[e + 4], xi[e + 4], wr, wi);
    }
  }
#pragma unroll
  for (int e = 0; e < 16; ++e) {            // m=2048: pairs (e,e+2), bit1==0
    if (((e >> 1) & 1) == 0) {
      int eb = e & 1;
      float wr = c4 * C4r[eb] - s4 * C4i[eb];
      float wi = c4 * C4i[eb] + s4 * C4r[eb];
      BFLY(xr[e], xi[e], xr[e + 2], xi[e + 2], wr, wi);
    }
  }
#pragma unroll
  for (int e = 0; e < 16; e += 2) {         // m=1024: pairs (e,e+1)
    BFLY(xr[e], xi[e], xr[e + 1], xi[e + 1], c8, s8);
  }

  // ---- exchange A->B ----
#pragma unroll
  for (int e = 0; e < 16; ++e) {
    int idx = t + (e << 9);
    int a = idx + (idx >> 5);
    zr[a] = xr[e];
    zi[a] = xi[e];
  }
  __syncthreads();
  {
    const int f = t >> 5, l = t & 31;
#pragma unroll
    for (int e = 0; e < 16; ++e) {
      int idx = (f << 9) + (e << 5) + l;
      int a = idx + (idx >> 5);
      xr[e] = zr[a];
      xi[e] = zi[a];
    }
    // ---- pass B: strides 256,128,64,32 in-register (within 512-block f) ----
    float bc1, bs1;
    sincosf(-PI2 * (float)l * (1.0f / 512.0f), &bs1, &bc1);
    float bc2 = bc1 * bc1 - bs1 * bs1, bs2 = 2.f * bc1 * bs1;
    float bc4 = bc2 * bc2 - bs2 * bs2, bs4 = 2.f * bc2 * bs2;
    float bc8 = bc4 * bc4 - bs4 * bs4, bs8 = 2.f * bc4 * bs4;
#pragma unroll
    for (int e = 0; e < 8; ++e) {           // m=512
      float wr = bc1 * C16r[e] - bs1 * C16i[e];
      float wi = bc1 * C16i[e] + bs1 * C16r[e];
      BFLY(xr[e], xi[e], xr[e + 8], xi[e + 8], wr, wi);
    }
#pragma unroll
    for (int e = 0; e < 16; ++e) {          // m=256
      if (((e >> 2) & 1) == 0) {
        int eb = e & 3;
        float wr = bc2 * C8r[eb] - bs2 * C8i[eb];
        float wi = bc2 * C8i[eb] + bs2 * C8r[eb];
        BFLY(xr[e], xi[e], xr[e + 4], xi[e + 4], wr, wi);
      }
    }
#pragma unroll
    for (int e = 0; e < 16; ++e) {          // m=128
      if (((e >> 1) & 1) == 0) {
        int eb = e & 1;
        float wr = bc4 * C4r[eb] - bs4 * C4i[eb];
        float wi = bc4 * C4i[eb] + bs4 * C4r[eb];
        BFLY(xr[e], xi[e], xr[e + 2], xi[e + 2], wr, wi);
      }
    }
#pragma unroll
    for (int e = 0; e < 16; e += 2) {       // m=64
      BFLY(xr[e], xi[e], xr[e + 1], xi[e + 1], bc8, bs8);
    }
    // ---- exchange B->C ----
    __syncthreads();
#pragma unroll
    for (int e = 0; e < 16; ++e) {
      int idx = (f << 9) + (e << 5) + l;
      int a = idx + (idx >> 5);
      zr[a] = xr[e];
      zi[a] = xi[e];
    }
  }
  __syncthreads();
#pragma unroll
  for (int j = 0; j < 16; ++j) {
    int idx = (t << 4) + j;
    int a = idx + (idx >> 5);
    xr[j] = zr[a];
    xi[j] = zi[a];
  }

  // ---- pass C: stride 16 via shfl, then 8,4,2,1 in-register ----
  {
    const int odd = t & 1;
#pragma unroll
    for (int j = 0; j < 16; ++j) {          // m=32 across thread pair
      float pr = __shfl_xor(xr[j], 1);
      float pi = __shfl_xor(xi[j], 1);
      if (!odd) {
        xr[j] += pr;
        xi[j] += pi;
      } else {
        float dr = pr - xr[j], di = pi - xi[j];   // a - b (a = partner)
        xr[j] = dr * C32r[j] - di * C32i[j];
        xi[j] = dr * C32i[j] + di * C32r[j];
      }
    }
#pragma unroll
    for (int j = 0; j < 8; ++j) {           // m=16
      BFLY(xr[j], xi[j], xr[j + 8], xi[j + 8], C16r[j], C16i[j]);
    }
#pragma unroll
    for (int j = 0; j < 16; ++j) {          // m=8
      if (((j >> 2) & 1) == 0) {
        BFLY(xr[j], xi[j], xr[j + 4], xi[j + 4], C8r[j & 3], C8i[j & 3]);
      }
    }
#pragma unroll
    for (int j = 0; j < 16; ++j) {          // m=4
      if (((j >> 1) & 1) == 0) {
        BFLY(xr[j], xi[j], xr[j + 2], xi[j + 2], C4r[j & 1], C4i[j & 1]);
      }
    }
#pragma unroll
    for (int j = 0; j < 16; j += 2) {       // m=2, tw = 1
      BFLY(xr[j], xi[j], xr[j + 1], xi[j + 1], 1.0f, 0.0f);
    }
  }

  // ---- bit-reversal scatter: z[16t+j] = X[rev13(16t+j)] ----
  __syncthreads();
  {
    const int rt = __brev((u32)t) >> 23;    // 9-bit reverse
#pragma unroll
    for (int j = 0; j < 16; ++j) {
      int k = (REV4[j] << 9) | rt;
      int a = k + (k >> 5);
      zr[a] = xr[j];
      zi[a] = xi[j];
    }
  }
  __syncthreads();

  // ---- unpack two real FFTs + coalesced store ----
  float* i0 = Xim + (((size_t)(b << 9) + d0) << 13);
  float* i1 = i0 + 8192;
#pragma unroll
  for (int e = 0; e < 16; ++e) {
    int k = t + (e << 9);
    int nk = (8192 - k) & 8191;
    int ka = k + (k >> 5), na = nk + (nk >> 5);
    float zrk = zr[ka], zik = zi[ka], zrn = zr[na], zin = zi[na];
    r0[k] = 0.5f * (zrk + zrn);
    i0[k] = 0.5f * (zik - zin);
    r1[k] = 0.5f * (zik + zin);
    i1[k] = 0.5f * (zrn - zrk);
  }
}

// ---------------- D-axis FFT (512-pt, register-blocked) + residual + LN1 ----------
// Block = 16 s-rows x 16 threads/row. Thread holds z[t+16e], e=0..31 in registers.
// 5 DIF stages in-register, one LDS exchange, two 16-pt FFTs in-register,
// bit-reversed Re-scatter to LDS, then residual+LN.
__global__ __launch_bounds__(256) void fft_d_ln(
    const float* __restrict__ Xre, const float* __restrict__ Xim,
    const float* __restrict__ x, const float* __restrict__ g1,
    const float* __restrict__ be1, u16* __restrict__ proj) {
  __shared__ float buf[16 * 528];           // 33792 B, one buffer for all phases
  const int tid = threadIdx.x;
  const int b = blockIdx.x >> 9;
  const int s0 = (blockIdx.x & 511) << 4;
  const int row = tid >> 4, t = tid & 15;   // compute roles
  const int so = tid & 15, dd = tid >> 4;   // staging roles

  float xr[32], xi[32];

  // ---- stage Xre -> LDS (layout A: a = s*516 + d), gather strided to regs ----
#pragma unroll
  for (int it = 0; it < 32; ++it) {
    int d = dd + (it << 4);
    buf[so * 516 + d] = Xre[(((size_t)(b << 9) + d) << 13) + s0 + so];
  }
  __syncthreads();
#pragma unroll
  for (int e = 0; e < 32; ++e) xr[e] = buf[row * 516 + t + (e << 4)];
  __syncthreads();
#pragma unroll
  for (int it = 0; it < 32; ++it) {
    int d = dd + (it << 4);
    buf[so * 516 + d] = Xim[(((size_t)(b << 9) + d) << 13) + s0 + so];
  }
  __syncthreads();
#pragma unroll
  for (int e = 0; e < 32; ++e) xi[e] = buf[row * 516 + t + (e << 4)];
  __syncthreads();

  // ---- 5 DIF stages in-register (strides 256,128,64,32,16) ----
  float c1, s1;
  sincosf(-PI2 * (float)t * (1.0f / 512.0f), &s1, &c1);
  float c2 = c1 * c1 - s1 * s1, s2 = 2.f * c1 * s1;    // W256^t
  float c4 = c2 * c2 - s2 * s2, s4 = 2.f * c2 * s2;    // W128^t
  float c8 = c4 * c4 - s4 * s4, s8 = 2.f * c4 * s4;    // W64^t
  float c16 = c8 * c8 - s8 * s8, s16 = 2.f * c8 * s8;  // W32^t
#pragma unroll
  for (int e = 0; e < 16; ++e) {            // half=256: pairs (e, e+16)
    float wr = c1 * C32r[e] - s1 * C32i[e];
    float wi = c1 * C32i[e] + s1 * C32r[e];
    BFLY(xr[e], xi[e], xr[e + 16], xi[e + 16], wr, wi);
  }
#pragma unroll
  for (int e = 0; e < 32; ++e) {            // half=128: pairs (e, e+8), (e&8)==0
    if ((e & 8) == 0) {
      int eb = e & 7;
      float wr = c2 * C16r[eb] - s2 * C16i[eb];
      float wi = c2 * C16i[eb] + s2 * C16r[eb];
      BFLY(xr[e], xi[e], xr[e + 8], xi[e + 8], wr, wi);
    }
  }
#pragma unroll
  for (int e = 0; e < 32; ++e) {            // half=64: pairs (e, e+4), (e&4)==0
    if ((e & 4) == 0) {
      int eb = e & 3;
      float wr = c4 * C8r[eb] - s4 * C8i[eb];
      float wi = c4 * C8i[eb] + s4 * C8r[eb];
      BFLY(xr[e], xi[e], xr[e + 4], xi[e + 4], wr, wi);
    }
  }
#pragma unroll
  for (int e = 0; e < 32; ++e) {            // half=32: pairs (e, e+2), (e&2)==0
    if ((e & 2) == 0) {
      int eb = e & 1;
      float wr = c8 * C4r[eb] - s8 * C4i[eb];
      float wi = c8 * C4i[eb] + s8 * C4r[eb];
      BFLY(xr[e], xi[e], xr[e + 2], xi[e + 2], wr, wi);
    }
  }
#pragma unroll
  for (int e = 0; e < 32; e += 2) {         // half=16: pairs (e, e+1), tw = W32^t
    BFLY(xr[e], xi[e], xr[e + 1], xi[e + 1], c16, s16);
  }

  // ---- exchange (layout B: a = row*528 + p + (p>>5)): thread gets blocks 2t,2t+1 --
#pragma unroll
  for (int e = 0; e < 32; ++e) {
    int p = (e << 4) + t;
    buf[row * 528 + p + (p >> 5)] = xr[e];
  }
  __syncthreads();
#pragma unroll
  for (int j = 0; j < 32; ++j) xr[j] = buf[row * 528 + 33 * t + j];
  __syncthreads();
#pragma unroll
  for (int e = 0; e < 32; ++e) {
    int p = (e << 4) + t;
    buf[row * 528 + p + (p >> 5)] = xi[e];
  }
  __syncthreads();
#pragma unroll
  for (int j = 0; j < 32; ++j) xi[j] = buf[row * 528 + 33 * t + j];
  __syncthreads();

  // ---- two 16-pt DIF FFTs in-register (blocks g=2t and g=2t+1) ----
#pragma unroll
  for (int o = 0; o < 32; o += 16) {
#pragma unroll
    for (int j = 0; j < 8; ++j)             // half=8
      BFLY(xr[o + j], xi[o + j], xr[o + j + 8], xi[o + j + 8], C16r[j], C16i[j]);
#pragma unroll
    for (int j = 0; j < 16; ++j)            // half=4
      if ((j & 4) == 0)
        BFLY(xr[o + j], xi[o + j], xr[o + j + 4], xi[o + j + 4], C8r[j & 3], C8i[j & 3]);
#pragma unroll
    for (int j = 0; j < 16; ++j)            // half=2
      if ((j & 2) == 0)
        BFLY(xr[o + j], xi[o + j], xr[o + j + 2], xi[o + j + 2], C4r[j & 1], C4i[j & 1]);
#pragma unroll
    for (int j = 0; j < 16; j += 2)         // half=1
      BFLY(xr[o + j], xi[o + j], xr[o + j + 1], xi[o + j + 1], 1.0f, 0.0f);
  }

  // ---- scatter Re at bit-reversed k (layout B): k = rev4(j)*32 + b*16 + rev4(t) ---
  {
    const int rt4 = __brev((u32)t) >> 28;
#pragma unroll
    for (int j = 0; j < 16; ++j) {
      const int rj = rev4c(j);
      buf[row * 528 + 33 * rj + rt4] = xr[j];            // block 2t   (b=0)
      buf[row * 528 + 33 * rj + 16 + rt4] = xr[16 + j];  // block 2t+1 (b=1)
    }
  }
  __syncthreads();

  // ---- residual add + LN over D=512 (16 threads per row) ----
  const int s = s0 + row;
  const float* xrow = x + (((size_t)(b << 13) + s) << 9);
  float v[32];
  float sum = 0.f, sum2 = 0.f;
#pragma unroll
  for (int m = 0; m < 32; ++m) {
    int d = t + (m << 4);
    float val = buf[row * 528 + d + (d >> 5)] + xrow[d];
    v[m] = val;
    sum += val;
    sum2 += val * val;
  }
#pragma unroll
  for (int m = 1; m < 16; m <<= 1) {
    sum += __shfl_xor(sum, m, 16);
    sum2 += __shfl_xor(sum2, m, 16);
  }
  float mean = sum * (1.0f / 512.0f);
  float var = sum2 * (1.0f / 512.0f) - mean * mean;
  float scl = 1.0f / sqrtf(var + LN_EPS);
  u16* prow = proj + (((size_t)(b << 13) + s) << 9);
#pragma unroll
  for (int m = 0; m < 32; ++m) {
    int d = t + (m << 4);
    prow[d] = f2bf((v[m] - mean) * scl * g1[d] + be1[d]);
  }
}

// ---------------- GEMM: C = act(A[MxK] * Bt[NxK]^T + bias), bf16 MFMA --------------
// m97 structure: 128x128 tile, 4 waves, BK=64, global_load_lds w16, XOR-swizzled LDS.
template <bool RELU, bool OUT_BF16>
__global__ __launch_bounds__(256, 2) void gemm_bt(
    const u16* __restrict__ A, const u16* __restrict__ Bt,
    const float* __restrict__ bias, void* __restrict__ Cout,
    int M, int N, int K) {
  const int tid = threadIdx.x;
  const int lane = tid & 63;
  const int wave = tid >> 6;
  const int wm = wave >> 1, wn = wave & 1;
  const int llo = lane & 15, lhi = lane >> 4;

  const int nwg = gridDim.x;                 // divisible by 8 for both launches
  const int q = nwg >> 3;
  const int b2 = ((int)blockIdx.x & 7) * q + ((int)blockIdx.x >> 3);  // XCD swizzle
  const int MT = M >> 7;
  const int tm = b2 % MT;
  const int tn = b2 / MT;
  const int m0 = tm << 7, n0 = tn << 7;

  __shared__ short8 smem[2048];              // 32 KB: A tile 16K + B tile 16K
  char* ldsA = (char*)&smem[0];
  char* ldsB = ldsA + 16384;

  f32x4 acc[4][4] = {};

  const int trow = tid >> 3;                                  // staging row 0..31
  const int ksw = (((tid & 7) ^ (trow & 7)) << 3);            // inverse-swizzled source k
  const int wbase = wave << 10;                               // wave-uniform LDS base
  const int swz = (llo & 7) << 4;                             // read-side XOR

  const int KT = K >> 6;
  for (int kt = 0; kt < KT; ++kt) {
    const int k0 = (kt << 6) + ksw;
    __syncthreads();                          // all waves done reading previous tile
#pragma unroll
    for (int r = 0; r < 4; ++r) {
      const int grow = (r << 5) + trow;
      const u16* ga = A + (size_t)(m0 + grow) * K + k0;
      const u16* gb = Bt + (size_t)(n0 + grow) * K + k0;
      __builtin_amdgcn_global_load_lds(
          (const __attribute__((address_space(1))) void*)ga,
          (__attribute__((address_space(3))) void*)(ldsA + (r << 12) + wbase), 16, 0, 0);
      __builtin_amdgcn_global_load_lds(
          (const __attribute__((address_space(1))) void*)gb,
          (__attribute__((address_space(3))) void*)(ldsB + (r << 12) + wbase), 16, 0, 0);
    }
    __syncthreads();                          // compiler drains vmcnt(0) here
#pragma unroll
    for (int kk = 0; kk < 2; ++kk) {
      const int cbx = ((kk << 6) | (lhi << 4)) ^ swz;
      short8 af[4], bfr[4];
#pragma unroll
      for (int mt = 0; mt < 4; ++mt)
        af[mt] = *(const short8*)(ldsA + (((wm << 6) + (mt << 4) + llo) << 7) + cbx);
#pragma unroll
      for (int nt = 0; nt < 4; ++nt)
        bfr[nt] = *(const short8*)(ldsB + (((wn << 6) + (nt << 4) + llo) << 7) + cbx);
#pragma unroll
      for (int mt = 0; mt < 4; ++mt)
#pragma unroll
        for (int nt = 0; nt < 4; ++nt)
          acc[mt][nt] =
              __builtin_amdgcn_mfma_f32_16x16x32_bf16(af[mt], bfr[nt], acc[mt][nt], 0, 0, 0);
    }
  }
  // epilogue: C/D map col=lane&15, row=(lane>>4)*4+j (guide-verified)
#pragma unroll
  for (int nt = 0; nt < 4; ++nt) {
    const int col = n0 + (wn << 6) + (nt << 4) + llo;
    const float bv = bias[col];
#pragma unroll
    for (int mt = 0; mt < 4; ++mt) {
      const int rbase = m0 + (wm << 6) + (mt << 4) + (lhi << 2);
#pragma unroll
      for (int j = 0; j < 4; ++j) {
        float v = acc[mt][nt][j] + bv;
        if (RELU) v = fmaxf(v, 0.0f);
        if (OUT_BF16) ((u16*)Cout)[(size_t)(rbase + j) * N + col] = f2bf(v);
        else          ((float*)Cout)[(size_t)(rbase + j) * N + col] = v;
      }
    }
  }
}

// ---------------- final residual + LayerNorm2 (wave per row, in-place on d_out) ----
__global__ __launch_bounds__(256) void ln2_kernel(
    float* __restrict__ out, const u16* __restrict__ proj,
    const float* __restrict__ g2, const float* __restrict__ be2) {
  const int lane = threadIdx.x & 63;
  const int row = blockIdx.x * 4 + (threadIdx.x >> 6);
  float* orow = out + ((size_t)row << 9);
  const u16* prow = proj + ((size_t)row << 9);
  float y[8];
  float sum = 0.f, sum2 = 0.f;
#pragma unroll
  for (int m = 0; m < 8; ++m) {
    int d = lane + (m << 6);
    float v = orow[d] + bf2f(prow[d]);
    y[m] = v; sum += v; sum2 += v * v;
  }
#pragma unroll
  for (int m = 1; m < 64; m <<= 1) {
    sum += __shfl_xor(sum, m, 64);
    sum2 += __shfl_xor(sum2, m, 64);
  }
  float mean = sum * (1.0f / 512.0f);
  float var = sum2 * (1.0f / 512.0f) - mean * mean;
  float scl = 1.0f / sqrtf(var + LN_EPS);
#pragma unroll
  for (int m = 0; m < 8; ++m) {
    int d = lane + (m << 6);
    orow[d] = (y[m] - mean) * scl * g2[d] + be2[d];
  }
}

// ---------------- launch ----------------
extern "C" void kernel_launch(void* const* d_in, const int* in_sizes, int n_in,
                              void* d_out, int out_size, void* d_ws, size_t ws_size,
                              hipStream_t stream) {
  const float* x   = (const float*)d_in[0];
  const float* W1  = (const float*)d_in[1];
  const float* b1  = (const float*)d_in[2];
  const float* W2  = (const float*)d_in[3];
  const float* b2  = (const float*)d_in[4];
  const float* g1  = (const float*)d_in[5];
  const float* be1 = (const float*)d_in[6];
  const float* g2  = (const float*)d_in[7];
  const float* be2 = (const float*)d_in[8];

  char* ws = (char*)d_ws;
  // layout (164 MB total):
  //   [0,64M)    xt -> Xre (in-place) -> first half of h
  //   [64M,128M) Xim -> second half of h
  //   [128M,160M) proj bf16
  //   [160M,162M) W1T bf16   [162M,164M) W2T bf16
  float* xre  = (float*)(ws);
  float* xim  = (float*)(ws + (64u << 20));
  u16*   proj = (u16*)(ws + (128u << 20));
  u16*   w1t  = (u16*)(ws + (160u << 20));
  u16*   w2t  = (u16*)(ws + (162u << 20));
  u16*   h    = (u16*)(ws);                  // 128 MB, aliases xre+xim (dead by then)

  prep_w<<<4096, 256, 0, stream>>>(W1, w1t, 512, 2048);
  prep_w<<<4096, 256, 0, stream>>>(W2, w2t, 2048, 512);
  transpose_x<<<16384, 256, 0, stream>>>(x, xre);
  fft_s<<<1024, 512, 0, stream>>>(xre, xim);
  fft_d_ln<<<2048, 256, 0, stream>>>(xre, xim, x, g1, be1, proj);
  gemm_bt<true, true><<<4096, 256, 0, stream>>>(proj, w1t, b1, (void*)h, 32768, 2048, 512);
  gemm_bt<false, false><<<1024, 256, 0, stream>>>(h, w2t, b2, d_out, 32768, 512, 2048);
  ln2_kernel<<<8192, 256, 0, stream>>>((float*)d_out, proj, g2, be2);
  (void)in_sizes; (void)n_in; (void)out_size; (void)ws_size;
}

// Round 4
// 331.997 us; speedup vs baseline: 1.5530x; 1.0925x over previous
//
#include <hip/hip_runtime.h>

typedef unsigned short u16;
typedef unsigned int u32;
typedef short short8 __attribute__((ext_vector_type(8)));
typedef float f32x4 __attribute__((ext_vector_type(4)));

#define LN_EPS 1e-3f
#define PI2 6.28318530717958647692f

__device__ __forceinline__ u16 f2bf(float f) {
  u32 u = __float_as_uint(f);
  u += 0x7fffu + ((u >> 16) & 1u);
  return (u16)(u >> 16);
}
__device__ __forceinline__ float bf2f(u16 h) {
  return __uint_as_float(((u32)h) << 16);
}

// ---------------- weight transpose + bf16 convert: W[R][C] f32 -> Wt[C][R] bf16 ----
__global__ void prep_w(const float* __restrict__ W, u16* __restrict__ Wt, int R, int C) {
  int idx = blockIdx.x * 256 + threadIdx.x;   // grid sized exactly R*C/256
  int n = idx / R;
  int k = idx - n * R;
  Wt[idx] = f2bf(W[(size_t)k * C + n]);
}

// ---------------- x[b][s][d] -> xt[b][d][s] (tiled 32x32) ----------------
__global__ __launch_bounds__(256) void transpose_x(const float* __restrict__ x,
                                                   float* __restrict__ xt) {
  __shared__ float tile[32][33];
  int blk = blockIdx.x;
  int b = blk >> 12;
  int rem = blk & 4095;
  int st = rem >> 4;   // s-tile 0..255
  int dt = rem & 15;   // d-tile 0..15
  int tx = threadIdx.x & 31, ty = threadIdx.x >> 5;
  int s0 = st << 5, d0 = dt << 5;
#pragma unroll
  for (int i = 0; i < 32; i += 8)
    tile[ty + i][tx] = x[(((size_t)(b << 13) + s0 + ty + i) << 9) + d0 + tx];
  __syncthreads();
#pragma unroll
  for (int i = 0; i < 32; i += 8)
    xt[(((size_t)(b << 9) + d0 + ty + i) << 13) + s0 + tx] = tile[tx][ty + i];
}

// ---------------- S-axis FFT (8192-pt DIF, register-blocked radix-16) --------------
// Two real columns packed per complex FFT. In: X=xt[b][d][s]. Out in-place:
// X = Re(FFT_S), Xim = Im(FFT_S).
// Twiddle constant tables W_n^k = exp(-2*pi*i*k/n): (cos, -sin)
__device__ __constant__ float C16r[8] = {1.f, 0.92387953f, 0.70710678f, 0.38268343f,
                                         0.f, -0.38268343f, -0.70710678f, -0.92387953f};
__device__ __constant__ float C16i[8] = {0.f, -0.38268343f, -0.70710678f, -0.92387953f,
                                         -1.f, -0.92387953f, -0.70710678f, -0.38268343f};
__device__ __constant__ float C8r[4] = {1.f, 0.70710678f, 0.f, -0.70710678f};
__device__ __constant__ float C8i[4] = {0.f, -0.70710678f, -1.f, -0.70710678f};
__device__ __constant__ float C4r[2] = {1.f, 0.f};
__device__ __constant__ float C4i[2] = {0.f, -1.f};
__device__ __constant__ float C32r[16] = {
    1.f, 0.98078528f, 0.92387953f, 0.83146961f, 0.70710678f, 0.55557023f,
    0.38268343f, 0.19509032f, 0.f, -0.19509032f, -0.38268343f, -0.55557023f,
    -0.70710678f, -0.83146961f, -0.92387953f, -0.98078528f};
__device__ __constant__ float C32i[16] = {
    0.f, -0.19509032f, -0.38268343f, -0.55557023f, -0.70710678f, -0.83146961f,
    -0.92387953f, -0.98078528f, -1.f, -0.98078528f, -0.92387953f, -0.83146961f,
    -0.70710678f, -0.55557023f, -0.38268343f, -0.19509032f};
__device__ __constant__ int REV4[16] = {0, 8, 4, 12, 2, 10, 6, 14,
                                        1, 9, 5, 13, 3, 11, 7, 15};

__device__ __forceinline__ constexpr int rev4c(int v) {
  return ((v & 1) << 3) | ((v & 2) << 1) | ((v & 4) >> 1) | ((v & 8) >> 3);
}

#define BFLY(ar, ai, br, bi, wr, wi)                 \
  {                                                  \
    float dr_ = (ar) - (br), di_ = (ai) - (bi);      \
    (ar) += (br);                                    \
    (ai) += (bi);                                    \
    (br) = dr_ * (wr)-di_ * (wi);                    \
    (bi) = dr_ * (wi) + di_ * (wr);                  \
  }

__global__ __launch_bounds__(512) void fft_s(float* __restrict__ X, float* __restrict__ Xim) {
  __shared__ float zr[8448], zi[8448];      // padded: addr(i) = i + (i>>5)
  const int t = threadIdx.x;
  const int b = blockIdx.x >> 8;
  const int d0 = (blockIdx.x & 255) << 1;
  float* r0 = X + (((size_t)(b << 9) + d0) << 13);
  float* r1 = r0 + 8192;

  float xr[16], xi[16];
#pragma unroll
  for (int e = 0; e < 16; ++e) {            // coalesced loads, idx = t + 512e
    xr[e] = r0[t + (e << 9)];
    xi[e] = r1[t + (e << 9)];
  }

  // ---- pass A: strides 4096,2048,1024,512 in-register ----
  float c1, s1;
  sincosf(-PI2 * (float)t * (1.0f / 8192.0f), &s1, &c1);
  float c2 = c1 * c1 - s1 * s1, s2 = 2.f * c1 * s1;
  float c4 = c2 * c2 - s2 * s2, s4 = 2.f * c2 * s2;
  float c8 = c4 * c4 - s4 * s4, s8 = 2.f * c4 * s4;
#pragma unroll
  for (int e = 0; e < 8; ++e) {             // m=8192
    float wr = c1 * C16r[e] - s1 * C16i[e];
    float wi = c1 * C16i[e] + s1 * C16r[e];
    BFLY(xr[e], xi[e], xr[e + 8], xi[e + 8], wr, wi);
  }
#pragma unroll
  for (int e = 0; e < 16; ++e) {            // m=4096: pairs (e,e+4), bit2==0
    if ((e & 4) == 0) {
      int eb = e & 3;
      float wr = c2 * C8r[eb] - s2 * C8i[eb];
      float wi = c2 * C8i[eb] + s2 * C8r[eb];
      BFLY(xr[e], xi[e], xr[e + 4], xi[e + 4], wr, wi);
    }
  }
#pragma unroll
  for (int e = 0; e < 16; ++e) {            // m=2048: pairs (e,e+2), bit1==0
    if (((e >> 1) & 1) == 0) {
      int eb = e & 1;
      float wr = c4 * C4r[eb] - s4 * C4i[eb];
      float wi = c4 * C4i[eb] + s4 * C4r[eb];
      BFLY(xr[e], xi[e], xr[e + 2], xi[e + 2], wr, wi);
    }
  }
#pragma unroll
  for (int e = 0; e < 16; e += 2) {         // m=1024: pairs (e,e+1)
    BFLY(xr[e], xi[e], xr[e + 1], xi[e + 1], c8, s8);
  }

  // ---- exchange A->B ----
#pragma unroll
  for (int e = 0; e < 16; ++e) {
    int idx = t + (e << 9);
    int a = idx + (idx >> 5);
    zr[a] = xr[e];
    zi[a] = xi[e];
  }
  __syncthreads();
  {
    const int f = t >> 5, l = t & 31;
#pragma unroll
    for (int e = 0; e < 16; ++e) {
      int idx = (f << 9) + (e << 5) + l;
      int a = idx + (idx >> 5);
      xr[e] = zr[a];
      xi[e] = zi[a];
    }
    // ---- pass B: strides 256,128,64,32 in-register (within 512-block f) ----
    float bc1, bs1;
    sincosf(-PI2 * (float)l * (1.0f / 512.0f), &bs1, &bc1);
    float bc2 = bc1 * bc1 - bs1 * bs1, bs2 = 2.f * bc1 * bs1;
    float bc4 = bc2 * bc2 - bs2 * bs2, bs4 = 2.f * bc2 * bs2;
    float bc8 = bc4 * bc4 - bs4 * bs4, bs8 = 2.f * bc4 * bs4;
#pragma unroll
    for (int e = 0; e < 8; ++e) {           // m=512
      float wr = bc1 * C16r[e] - bs1 * C16i[e];
      float wi = bc1 * C16i[e] + bs1 * C16r[e];
      BFLY(xr[e], xi[e], xr[e + 8], xi[e + 8], wr, wi);
    }
#pragma unroll
    for (int e = 0; e < 16; ++e) {          // m=256
      if (((e >> 2) & 1) == 0) {
        int eb = e & 3;
        float wr = bc2 * C8r[eb] - bs2 * C8i[eb];
        float wi = bc2 * C8i[eb] + bs2 * C8r[eb];
        BFLY(xr[e], xi[e], xr[e + 4], xi[e + 4], wr, wi);
      }
    }
#pragma unroll
    for (int e = 0; e < 16; ++e) {          // m=128
      if (((e >> 1) & 1) == 0) {
        int eb = e & 1;
        float wr = bc4 * C4r[eb] - bs4 * C4i[eb];
        float wi = bc4 * C4i[eb] + bs4 * C4r[eb];
        BFLY(xr[e], xi[e], xr[e + 2], xi[e + 2], wr, wi);
      }
    }
#pragma unroll
    for (int e = 0; e < 16; e += 2) {       // m=64
      BFLY(xr[e], xi[e], xr[e + 1], xi[e + 1], bc8, bs8);
    }
    // ---- exchange B->C ----
    __syncthreads();
#pragma unroll
    for (int e = 0; e < 16; ++e) {
      int idx = (f << 9) + (e << 5) + l;
      int a = idx + (idx >> 5);
      zr[a] = xr[e];
      zi[a] = xi[e];
    }
  }
  __syncthreads();
#pragma unroll
  for (int j = 0; j < 16; ++j) {
    int idx = (t << 4) + j;
    int a = idx + (idx >> 5);
    xr[j] = zr[a];
    xi[j] = zi[a];
  }

  // ---- pass C: stride 16 via shfl, then 8,4,2,1 in-register ----
  {
    const int odd = t & 1;
#pragma unroll
    for (int j = 0; j < 16; ++j) {          // m=32 across thread pair
      float pr = __shfl_xor(xr[j], 1);
      float pi = __shfl_xor(xi[j], 1);
      if (!odd) {
        xr[j] += pr;
        xi[j] += pi;
      } else {
        float dr = pr - xr[j], di = pi - xi[j];   // a - b (a = partner)
        xr[j] = dr * C32r[j] - di * C32i[j];
        xi[j] = dr * C32i[j] + di * C32r[j];
      }
    }
#pragma unroll
    for (int j = 0; j < 8; ++j) {           // m=16
      BFLY(xr[j], xi[j], xr[j + 8], xi[j + 8], C16r[j], C16i[j]);
    }
#pragma unroll
    for (int j = 0; j < 16; ++j) {          // m=8
      if (((j >> 2) & 1) == 0) {
        BFLY(xr[j], xi[j], xr[j + 4], xi[j + 4], C8r[j & 3], C8i[j & 3]);
      }
    }
#pragma unroll
    for (int j = 0; j < 16; ++j) {          // m=4
      if (((j >> 1) & 1) == 0) {
        BFLY(xr[j], xi[j], xr[j + 2], xi[j + 2], C4r[j & 1], C4i[j & 1]);
      }
    }
#pragma unroll
    for (int j = 0; j < 16; j += 2) {       // m=2, tw = 1
      BFLY(xr[j], xi[j], xr[j + 1], xi[j + 1], 1.0f, 0.0f);
    }
  }

  // ---- bit-reversal scatter: z[16t+j] = X[rev13(16t+j)] ----
  __syncthreads();
  {
    const int rt = __brev((u32)t) >> 23;    // 9-bit reverse
#pragma unroll
    for (int j = 0; j < 16; ++j) {
      int k = (REV4[j] << 9) | rt;
      int a = k + (k >> 5);
      zr[a] = xr[j];
      zi[a] = xi[j];
    }
  }
  __syncthreads();

  // ---- unpack two real FFTs + coalesced store ----
  float* i0 = Xim + (((size_t)(b << 9) + d0) << 13);
  float* i1 = i0 + 8192;
#pragma unroll
  for (int e = 0; e < 16; ++e) {
    int k = t + (e << 9);
    int nk = (8192 - k) & 8191;
    int ka = k + (k >> 5), na = nk + (nk >> 5);
    float zrk = zr[ka], zik = zi[ka], zrn = zr[na], zin = zi[na];
    r0[k] = 0.5f * (zrk + zrn);
    i0[k] = 0.5f * (zik - zin);
    r1[k] = 0.5f * (zik + zin);
    i1[k] = 0.5f * (zrn - zrk);
  }
}

// ---------------- D-axis FFT (512-pt, register-blocked) + residual + LN1 ----------
// Block = 16 s-rows x 16 threads/row. Thread holds z[t+16e], e=0..31 in registers.
__global__ __launch_bounds__(256) void fft_d_ln(
    const float* __restrict__ Xre, const float* __restrict__ Xim,
    const float* __restrict__ x, const float* __restrict__ g1,
    const float* __restrict__ be1, u16* __restrict__ proj) {
  __shared__ float buf[16 * 528];           // 33792 B, one buffer for all phases
  const int tid = threadIdx.x;
  const int b = blockIdx.x >> 9;
  const int s0 = (blockIdx.x & 511) << 4;
  const int row = tid >> 4, t = tid & 15;   // compute roles
  const int so = tid & 15, dd = tid >> 4;   // staging roles

  float xr[32], xi[32];

  // ---- stage Xre -> LDS (layout A: a = s*516 + d), gather strided to regs ----
#pragma unroll
  for (int it = 0; it < 32; ++it) {
    int d = dd + (it << 4);
    buf[so * 516 + d] = Xre[(((size_t)(b << 9) + d) << 13) + s0 + so];
  }
  __syncthreads();
#pragma unroll
  for (int e = 0; e < 32; ++e) xr[e] = buf[row * 516 + t + (e << 4)];
  __syncthreads();
#pragma unroll
  for (int it = 0; it < 32; ++it) {
    int d = dd + (it << 4);
    buf[so * 516 + d] = Xim[(((size_t)(b << 9) + d) << 13) + s0 + so];
  }
  __syncthreads();
#pragma unroll
  for (int e = 0; e < 32; ++e) xi[e] = buf[row * 516 + t + (e << 4)];
  __syncthreads();

  // ---- 5 DIF stages in-register (strides 256,128,64,32,16) ----
  float c1, s1;
  sincosf(-PI2 * (float)t * (1.0f / 512.0f), &s1, &c1);
  float c2 = c1 * c1 - s1 * s1, s2 = 2.f * c1 * s1;    // W256^t
  float c4 = c2 * c2 - s2 * s2, s4 = 2.f * c2 * s2;    // W128^t
  float c8 = c4 * c4 - s4 * s4, s8 = 2.f * c4 * s4;    // W64^t
  float c16 = c8 * c8 - s8 * s8, s16 = 2.f * c8 * s8;  // W32^t
#pragma unroll
  for (int e = 0; e < 16; ++e) {            // half=256: pairs (e, e+16)
    float wr = c1 * C32r[e] - s1 * C32i[e];
    float wi = c1 * C32i[e] + s1 * C32r[e];
    BFLY(xr[e], xi[e], xr[e + 16], xi[e + 16], wr, wi);
  }
#pragma unroll
  for (int e = 0; e < 32; ++e) {            // half=128: pairs (e, e+8), (e&8)==0
    if ((e & 8) == 0) {
      int eb = e & 7;
      float wr = c2 * C16r[eb] - s2 * C16i[eb];
      float wi = c2 * C16i[eb] + s2 * C16r[eb];
      BFLY(xr[e], xi[e], xr[e + 8], xi[e + 8], wr, wi);
    }
  }
#pragma unroll
  for (int e = 0; e < 32; ++e) {            // half=64: pairs (e, e+4), (e&4)==0
    if ((e & 4) == 0) {
      int eb = e & 3;
      float wr = c4 * C8r[eb] - s4 * C8i[eb];
      float wi = c4 * C8i[eb] + s4 * C8r[eb];
      BFLY(xr[e], xi[e], xr[e + 4], xi[e + 4], wr, wi);
    }
  }
#pragma unroll
  for (int e = 0; e < 32; ++e) {            // half=32: pairs (e, e+2), (e&2)==0
    if ((e & 2) == 0) {
      int eb = e & 1;
      float wr = c8 * C4r[eb] - s8 * C4i[eb];
      float wi = c8 * C4i[eb] + s8 * C4r[eb];
      BFLY(xr[e], xi[e], xr[e + 2], xi[e + 2], wr, wi);
    }
  }
#pragma unroll
  for (int e = 0; e < 32; e += 2) {         // half=16: pairs (e, e+1), tw = W32^t
    BFLY(xr[e], xi[e], xr[e + 1], xi[e + 1], c16, s16);
  }

  // ---- exchange (layout B: a = row*528 + p + (p>>5)): thread gets blocks 2t,2t+1 --
#pragma unroll
  for (int e = 0; e < 32; ++e) {
    int p = (e << 4) + t;
    buf[row * 528 + p + (p >> 5)] = xr[e];
  }
  __syncthreads();
#pragma unroll
  for (int j = 0; j < 32; ++j) xr[j] = buf[row * 528 + 33 * t + j];
  __syncthreads();
#pragma unroll
  for (int e = 0; e < 32; ++e) {
    int p = (e << 4) + t;
    buf[row * 528 + p + (p >> 5)] = xi[e];
  }
  __syncthreads();
#pragma unroll
  for (int j = 0; j < 32; ++j) xi[j] = buf[row * 528 + 33 * t + j];
  __syncthreads();

  // ---- two 16-pt DIF FFTs in-register (blocks g=2t and g=2t+1) ----
#pragma unroll
  for (int o = 0; o < 32; o += 16) {
#pragma unroll
    for (int j = 0; j < 8; ++j)             // half=8
      BFLY(xr[o + j], xi[o + j], xr[o + j + 8], xi[o + j + 8], C16r[j], C16i[j]);
#pragma unroll
    for (int j = 0; j < 16; ++j)            // half=4
      if ((j & 4) == 0)
        BFLY(xr[o + j], xi[o + j], xr[o + j + 4], xi[o + j + 4], C8r[j & 3], C8i[j & 3]);
#pragma unroll
    for (int j = 0; j < 16; ++j)            // half=2
      if ((j & 2) == 0)
        BFLY(xr[o + j], xi[o + j], xr[o + j + 2], xi[o + j + 2], C4r[j & 1], C4i[j & 1]);
#pragma unroll
    for (int j = 0; j < 16; j += 2)         // half=1
      BFLY(xr[o + j], xi[o + j], xr[o + j + 1], xi[o + j + 1], 1.0f, 0.0f);
  }

  // ---- scatter Re at bit-reversed k (layout B): k = rev4(j)*32 + b*16 + rev4(t) ---
  {
    const int rt4 = __brev((u32)t) >> 28;
#pragma unroll
    for (int j = 0; j < 16; ++j) {
      const int rj = rev4c(j);
      buf[row * 528 + 33 * rj + rt4] = xr[j];            // block 2t   (b=0)
      buf[row * 528 + 33 * rj + 16 + rt4] = xr[16 + j];  // block 2t+1 (b=1)
    }
  }
  __syncthreads();

  // ---- residual add + LN over D=512 (16 threads per row) ----
  const int s = s0 + row;
  const float* xrow = x + (((size_t)(b << 13) + s) << 9);
  float v[32];
  float sum = 0.f, sum2 = 0.f;
#pragma unroll
  for (int m = 0; m < 32; ++m) {
    int d = t + (m << 4);
    float val = buf[row * 528 + d + (d >> 5)] + xrow[d];
    v[m] = val;
    sum += val;
    sum2 += val * val;
  }
#pragma unroll
  for (int m = 1; m < 16; m <<= 1) {
    sum += __shfl_xor(sum, m, 16);
    sum2 += __shfl_xor(sum2, m, 16);
  }
  float mean = sum * (1.0f / 512.0f);
  float var = sum2 * (1.0f / 512.0f) - mean * mean;
  float scl = 1.0f / sqrtf(var + LN_EPS);
  u16* prow = proj + (((size_t)(b << 13) + s) << 9);
#pragma unroll
  for (int m = 0; m < 32; ++m) {
    int d = t + (m << 4);
    prow[d] = f2bf((v[m] - mean) * scl * g1[d] + be1[d]);
  }
}

// ---------------- GEMM: C = act(A[MxK] * Bt[NxK]^T + bias), bf16 MFMA --------------
// m97 structure + grouped tile order: GH row-tiles share L2 across all NT col-tiles.
template <bool RELU, bool OUT_BF16, int GH>
__global__ __launch_bounds__(256, 2) void gemm_bt(
    const u16* __restrict__ A, const u16* __restrict__ Bt,
    const float* __restrict__ bias, void* __restrict__ Cout,
    int M, int N, int K) {
  const int tid = threadIdx.x;
  const int lane = tid & 63;
  const int wave = tid >> 6;
  const int wm = wave >> 1, wn = wave & 1;
  const int llo = lane & 15, lhi = lane >> 4;

  const int nwg = gridDim.x;                 // divisible by 8 and by GH*NT
  const int q = nwg >> 3;
  const int b2 = ((int)blockIdx.x & 7) * q + ((int)blockIdx.x >> 3);  // XCD chunk
  const int NT = N >> 7;
  const int GSZ = GH * NT;
  const int grp = b2 / GSZ;                  // group of GH row-tiles
  const int r = b2 - grp * GSZ;
  const int tn = r / GH;                     // column-tile (slow within group)
  const int tm = grp * GH + (r - tn * GH);   // row-tile (fast within group)
  const int m0 = tm << 7, n0 = tn << 7;

  __shared__ short8 smem[2048];              // 32 KB: A tile 16K + B tile 16K
  char* ldsA = (char*)&smem[0];
  char* ldsB = ldsA + 16384;

  f32x4 acc[4][4] = {};

  const int trow = tid >> 3;                                  // staging row 0..31
  const int ksw = (((tid & 7) ^ (trow & 7)) << 3);            // inverse-swizzled source k
  const int wbase = wave << 10;                               // wave-uniform LDS base
  const int swz = (llo & 7) << 4;                             // read-side XOR

  const int KT = K >> 6;
  for (int kt = 0; kt < KT; ++kt) {
    const int k0 = (kt << 6) + ksw;
    __syncthreads();                          // all waves done reading previous tile
#pragma unroll
    for (int r4 = 0; r4 < 4; ++r4) {
      const int grow = (r4 << 5) + trow;
      const u16* ga = A + (size_t)(m0 + grow) * K + k0;
      const u16* gb = Bt + (size_t)(n0 + grow) * K + k0;
      __builtin_amdgcn_global_load_lds(
          (const __attribute__((address_space(1))) void*)ga,
          (__attribute__((address_space(3))) void*)(ldsA + (r4 << 12) + wbase), 16, 0, 0);
      __builtin_amdgcn_global_load_lds(
          (const __attribute__((address_space(1))) void*)gb,
          (__attribute__((address_space(3))) void*)(ldsB + (r4 << 12) + wbase), 16, 0, 0);
    }
    __syncthreads();                          // compiler drains vmcnt(0) here
#pragma unroll
    for (int kk = 0; kk < 2; ++kk) {
      const int cbx = ((kk << 6) | (lhi << 4)) ^ swz;
      short8 af[4], bfr[4];
#pragma unroll
      for (int mt = 0; mt < 4; ++mt)
        af[mt] = *(const short8*)(ldsA + (((wm << 6) + (mt << 4) + llo) << 7) + cbx);
#pragma unroll
      for (int nt = 0; nt < 4; ++nt)
        bfr[nt] = *(const short8*)(ldsB + (((wn << 6) + (nt << 4) + llo) << 7) + cbx);
#pragma unroll
      for (int mt = 0; mt < 4; ++mt)
#pragma unroll
        for (int nt = 0; nt < 4; ++nt)
          acc[mt][nt] =
              __builtin_amdgcn_mfma_f32_16x16x32_bf16(af[mt], bfr[nt], acc[mt][nt], 0, 0, 0);
    }
  }
  // epilogue: C/D map col=lane&15, row=(lane>>4)*4+j (guide-verified)
#pragma unroll
  for (int nt = 0; nt < 4; ++nt) {
    const int col = n0 + (wn << 6) + (nt << 4) + llo;
    const float bv = bias[col];
#pragma unroll
    for (int mt = 0; mt < 4; ++mt) {
      const int rbase = m0 + (wm << 6) + (mt << 4) + (lhi << 2);
#pragma unroll
      for (int j = 0; j < 4; ++j) {
        float v = acc[mt][nt][j] + bv;
        if (RELU) v = fmaxf(v, 0.0f);
        if (OUT_BF16) ((u16*)Cout)[(size_t)(rbase + j) * N + col] = f2bf(v);
        else          ((float*)Cout)[(size_t)(rbase + j) * N + col] = v;
      }
    }
  }
}

// ---------------- final residual + LayerNorm2 (wave per row, vectorized) -----------
__global__ __launch_bounds__(256) void ln2_kernel(
    float* __restrict__ out, const u16* __restrict__ proj,
    const float* __restrict__ g2, const float* __restrict__ be2) {
  const int lane = threadIdx.x & 63;
  const int row = blockIdx.x * 4 + (threadIdx.x >> 6);
  float* orow = out + ((size_t)row << 9);
  const u16* prow = proj + ((size_t)row << 9);
  const int d0 = lane << 3;                  // 8 contiguous elems per lane
  f32x4 a0 = *(const f32x4*)(orow + d0);
  f32x4 a1 = *(const f32x4*)(orow + d0 + 4);
  short8 p = *(const short8*)(prow + d0);
  float y[8];
  float sum = 0.f, sum2 = 0.f;
#pragma unroll
  for (int m = 0; m < 8; ++m) {
    float v = (m < 4 ? a0[m] : a1[m - 4]) + bf2f((u16)p[m]);
    y[m] = v; sum += v; sum2 += v * v;
  }
#pragma unroll
  for (int m = 1; m < 64; m <<= 1) {
    sum += __shfl_xor(sum, m, 64);
    sum2 += __shfl_xor(sum2, m, 64);
  }
  float mean = sum * (1.0f / 512.0f);
  float var = sum2 * (1.0f / 512.0f) - mean * mean;
  float scl = 1.0f / sqrtf(var + LN_EPS);
  f32x4 g0 = *(const f32x4*)(g2 + d0);
  f32x4 g1v = *(const f32x4*)(g2 + d0 + 4);
  f32x4 e0 = *(const f32x4*)(be2 + d0);
  f32x4 e1 = *(const f32x4*)(be2 + d0 + 4);
  f32x4 o0, o1;
#pragma unroll
  for (int m = 0; m < 4; ++m) o0[m] = (y[m] - mean) * scl * g0[m] + e0[m];
#pragma unroll
  for (int m = 0; m < 4; ++m) o1[m] = (y[m + 4] - mean) * scl * g1v[m] + e1[m];
  *(f32x4*)(orow + d0) = o0;
  *(f32x4*)(orow + d0 + 4) = o1;
}

// ---------------- launch ----------------
extern "C" void kernel_launch(void* const* d_in, const int* in_sizes, int n_in,
                              void* d_out, int out_size, void* d_ws, size_t ws_size,
                              hipStream_t stream) {
  const float* x   = (const float*)d_in[0];
  const float* W1  = (const float*)d_in[1];
  const float* b1  = (const float*)d_in[2];
  const float* W2  = (const float*)d_in[3];
  const float* b2  = (const float*)d_in[4];
  const float* g1  = (const float*)d_in[5];
  const float* be1 = (const float*)d_in[6];
  const float* g2  = (const float*)d_in[7];
  const float* be2 = (const float*)d_in[8];

  char* ws = (char*)d_ws;
  // layout (164 MB total):
  //   [0,64M)    xt -> Xre (in-place) -> first half of h
  //   [64M,128M) Xim -> second half of h
  //   [128M,160M) proj bf16
  //   [160M,162M) W1T bf16   [162M,164M) W2T bf16
  float* xre  = (float*)(ws);
  float* xim  = (float*)(ws + (64u << 20));
  u16*   proj = (u16*)(ws + (128u << 20));
  u16*   w1t  = (u16*)(ws + (160u << 20));
  u16*   w2t  = (u16*)(ws + (162u << 20));
  u16*   h    = (u16*)(ws);                  // 128 MB, aliases xre+xim (dead by then)

  prep_w<<<4096, 256, 0, stream>>>(W1, w1t, 512, 2048);
  prep_w<<<4096, 256, 0, stream>>>(W2, w2t, 2048, 512);
  transpose_x<<<16384, 256, 0, stream>>>(x, xre);
  fft_s<<<1024, 512, 0, stream>>>(xre, xim);
  fft_d_ln<<<2048, 256, 0, stream>>>(xre, xim, x, g1, be1, proj);
  // GEMM1: GH=8 -> group ws = 8*128KB A + 16*128KB B = 3MB < 4MB L2
  gemm_bt<true, true, 8><<<4096, 256, 0, stream>>>(proj, w1t, b1, (void*)h, 32768, 2048, 512);
  // GEMM2: GH=4 -> group ws = 4*512KB A + 4*512KB B = 4MB
  gemm_bt<false, false, 4><<<1024, 256, 0, stream>>>(h, w2t, b2, d_out, 32768, 512, 2048);
  ln2_kernel<<<8192, 256, 0, stream>>>((float*)d_out, proj, g2, be2);
  (void)in_sizes; (void)n_in; (void)out_size; (void)ws_size;
}